// Round 1
// 950.465 us; speedup vs baseline: 1.6321x; 1.6321x over previous
//
#include <hip/hip_runtime.h>

// ============================================================================
// train_model_27925877358676 — round 5:
//  (1) scatter_add (65.5M fp32 atomics, 216us, WRITE 260MB) -> CSR build +
//      per-dst gather-mean fused with bf16 hi/lo split write.
//  (2) ALL fp32 gemm_bt calls -> bf16 MFMA. Exact-bf16 operands (x, ppr,
//      weights) convert losslessly; full-mantissa operands use hi/lo split
//      (rel err ~2^-16) with K-concat vs duplicated weights.
//  (3) xp1 MFMA: split-K=5 (320 blocks vs 64); xp2 split-K=2. Partials+reduce.
// ws ≈ 139 MiB (fp32 57.3 MB + bf16 88.5 MB).
// ============================================================================

typedef unsigned short ushort;
typedef __attribute__((ext_vector_type(8))) short short8;   // 8 bf16
typedef __attribute__((ext_vector_type(4))) float float4v;  // 4 fp32 acc

__device__ __forceinline__ ushort bf16_rne(float v) {
    unsigned u = __float_as_uint(v);
    u += 0x7fffu + ((u >> 16) & 1u);
    return (ushort)(u >> 16);
}
__device__ __forceinline__ float bf16_f32(ushort h) {
    return __uint_as_float((unsigned)h << 16);
}

// ---------------- workspace layout (file-scope so kernels can share) -------
// fp32 region (float offsets)
constexpr long ZCNT0 = 0;          // int[8000]  (zeroed)
constexpr long ZCNT1 = 8000;       // int[2000]  (zeroed)
constexpr long ZLOSS = 10000;      // float      (zeroed)
constexpr long ZEND  = 10240;
constexpr long OFF0  = 10240;      // int[8000]
constexpr long CUR0  = 18240;      // int[8000]
constexpr long OFF1  = 26240;      // int[2000]
constexpr long CUR1  = 28240;      // int[2000]
constexpr long EID0  = 30240;      // int[128000]
constexpr long EID1  = 158240;     // int[32000]
constexpr long H1    = 190240;     // f[8064*256]
constexpr long H2    = 2254624;    // f[2048*256]
constexpr long DIVC  = 2778912;    // f[2048*512]
constexpr long XP1   = 3827488;    // f[2048*512]
constexpr long XP2   = 4876064;    // f[2048*512]
constexpr long XPA   = 5924640;    // f[2048*512]
constexpr long XPBF  = 6973216;    // f[2048*256]
constexpr long GB    = 7497504;    // f[2048*256]
constexpr long TB    = 8021792;    // f[2048*256]
constexpr long PB    = 8546080;    // f[2048*256]
constexpr long PART  = 9070368;    // f[5*2048*512] split-K partials
constexpr long FEND  = 14313248;
// bf16 region (ushort offsets from uws)
constexpr long U_PPRB  = 0;         // [2048][8000]
constexpr long U_PPR2B = 16384000;  // [2048][2048]
constexpr long U_XTB   = 20578304;  // [512][8000]
constexpr long U_XPATB = 24674304;  // [512][2048]
constexpr long U_XB    = 25722880;  // [8064][512]
constexpr long U_A0B   = 29851648;  // [8064][1024] = [agg_hi|agg_lo]
constexpr long U_SCR   = 38109184;  // [2048][1024] shared scratch (2 slots)
constexpr long U_XPS   = 40206336;  // [2048][1024] xp split
constexpr long U_WRB   = 42303488;  // [256][512]   Wr0
constexpr long U_WL0D  = 42434560;  // [256][1024]  [Wl0|Wl0]
constexpr long U_WR1D  = 42696704;  // [256][512]   [Wr1|Wr1]
constexpr long U_WL1D  = 42827776;  // [256][512]   [Wl1|Wl1]
constexpr long U_BD    = 42958848;  // [512][512]   [[W1|W1];[W2|W2]]
constexpr long U_WAD   = 43220992;  // [512][1024]  [Wa|Wa]
constexpr long U_WBD   = 43745280;  // [256][1024]  [Wb|Wb]
constexpr long U_WP1D  = 44007424;  // [256][512]   [Wp1|Wp1]
constexpr long U_WP2D  = 44138496;  // [256][512]   [Wp2|Wp2]

// ---------------------------------------------------------------------------
// MFMA B^T GEMM: C[M,N] = op( A[M,K] @ B[N,K]^T ), bf16 in, fp32 out.
// M = gridDim.y*128, N = gridDim.x*128 exactly; K % 32 == 0, pads zero.
// flags: bit0 = beta (C += ...), bit1 = relu. bias nullable (len N).
// ---------------------------------------------------------------------------
__global__ __launch_bounds__(256) void mfma_bt(
    const ushort* __restrict__ A, const ushort* __restrict__ B,
    float* __restrict__ C, int K, int lda, int ldb, int ldc,
    const float* __restrict__ bias, int flags)
{
    __shared__ ushort As[128 * 32];
    __shared__ ushort Bs[128 * 32];
    const int tid = threadIdx.x;
    const int lane = tid & 63, wave = tid >> 6;
    const int wm = (wave >> 1) * 64, wn = (wave & 1) * 64;
    const int lr = lane & 15, quad = lane >> 4;
    const int bm = blockIdx.y * 128, bn = blockIdx.x * 128;

    float4v acc[4][4] = {{{0.f, 0.f, 0.f, 0.f}}};

    for (int k0 = 0; k0 < K; k0 += 32) {
#pragma unroll
        for (int issue = 0; issue < 2; ++issue) {
            int c = issue * 256 + tid;
            int r = c >> 2, p = (c & 3) * 8;
            const ushort* ga = A + (long)(bm + r) * lda + k0 + p;
            const ushort* gb = B + (long)(bn + r) * ldb + k0 + p;
            __builtin_amdgcn_global_load_lds(
                (const __attribute__((address_space(1))) unsigned int*)ga,
                (__attribute__((address_space(3))) unsigned int*)&As[c * 8], 16, 0, 0);
            __builtin_amdgcn_global_load_lds(
                (const __attribute__((address_space(1))) unsigned int*)gb,
                (__attribute__((address_space(3))) unsigned int*)&Bs[c * 8], 16, 0, 0);
        }
        __syncthreads();

        short8 af[4], bf[4];
#pragma unroll
        for (int i = 0; i < 4; ++i) {
            af[i] = *(const short8*)&As[(wm + i * 16 + lr) * 32 + quad * 8];
            bf[i] = *(const short8*)&Bs[(wn + i * 16 + lr) * 32 + quad * 8];
        }
#pragma unroll
        for (int i = 0; i < 4; ++i)
#pragma unroll
            for (int j = 0; j < 4; ++j)
                acc[i][j] = __builtin_amdgcn_mfma_f32_16x16x32_bf16(
                    af[i], bf[j], acc[i][j], 0, 0, 0);
        __syncthreads();
    }

#pragma unroll
    for (int i = 0; i < 4; ++i) {
        int row0 = bm + wm + i * 16 + quad * 4;
#pragma unroll
        for (int j = 0; j < 4; ++j) {
            int col = bn + wn + j * 16 + lr;
            float bv = bias ? bias[col] : 0.f;
#pragma unroll
            for (int r = 0; r < 4; ++r) {
                float v = acc[i][j][r];
                if (flags & 1) v += C[(long)(row0 + r) * ldc + col];
                v += bv;
                if (flags & 2) v = fmaxf(v, 0.f);
                C[(long)(row0 + r) * ldc + col] = v;
            }
        }
    }
}

// split-K variant: grid.z = K-chunk index, writes partial z at Cp + z*M*N.
__global__ __launch_bounds__(256) void mfma_bt_sk(
    const ushort* __restrict__ A, const ushort* __restrict__ B,
    float* __restrict__ Cp, int K, int kchunk, int lda, int ldb, int ldc)
{
    __shared__ ushort As[128 * 32];
    __shared__ ushort Bs[128 * 32];
    const int tid = threadIdx.x;
    const int lane = tid & 63, wave = tid >> 6;
    const int wm = (wave >> 1) * 64, wn = (wave & 1) * 64;
    const int lr = lane & 15, quad = lane >> 4;
    const int bm = blockIdx.y * 128, bn = blockIdx.x * 128;
    const int kbeg = blockIdx.z * kchunk;
    const int kend = (kbeg + kchunk < K) ? (kbeg + kchunk) : K;
    float* C = Cp + (long)blockIdx.z * (long)(gridDim.x * 128) * (long)(gridDim.y * 128);

    float4v acc[4][4] = {{{0.f, 0.f, 0.f, 0.f}}};

    for (int k0 = kbeg; k0 < kend; k0 += 32) {
#pragma unroll
        for (int issue = 0; issue < 2; ++issue) {
            int c = issue * 256 + tid;
            int r = c >> 2, p = (c & 3) * 8;
            const ushort* ga = A + (long)(bm + r) * lda + k0 + p;
            const ushort* gb = B + (long)(bn + r) * ldb + k0 + p;
            __builtin_amdgcn_global_load_lds(
                (const __attribute__((address_space(1))) unsigned int*)ga,
                (__attribute__((address_space(3))) unsigned int*)&As[c * 8], 16, 0, 0);
            __builtin_amdgcn_global_load_lds(
                (const __attribute__((address_space(1))) unsigned int*)gb,
                (__attribute__((address_space(3))) unsigned int*)&Bs[c * 8], 16, 0, 0);
        }
        __syncthreads();

        short8 af[4], bf[4];
#pragma unroll
        for (int i = 0; i < 4; ++i) {
            af[i] = *(const short8*)&As[(wm + i * 16 + lr) * 32 + quad * 8];
            bf[i] = *(const short8*)&Bs[(wn + i * 16 + lr) * 32 + quad * 8];
        }
#pragma unroll
        for (int i = 0; i < 4; ++i)
#pragma unroll
            for (int j = 0; j < 4; ++j)
                acc[i][j] = __builtin_amdgcn_mfma_f32_16x16x32_bf16(
                    af[i], bf[j], acc[i][j], 0, 0, 0);
        __syncthreads();
    }

#pragma unroll
    for (int i = 0; i < 4; ++i) {
        int row0 = bm + wm + i * 16 + quad * 4;
#pragma unroll
        for (int j = 0; j < 4; ++j) {
            int col = bn + wn + j * 16 + lr;
#pragma unroll
            for (int r = 0; r < 4; ++r)
                C[(long)(row0 + r) * ldc + col] = acc[i][j][r];
        }
    }
}

__global__ __launch_bounds__(256) void reduce_parts(
    const float* __restrict__ part, float* __restrict__ out, long n, int S)
{
    long i = (long)blockIdx.x * 256 + threadIdx.x;
    if (i < n) {
        float s = 0.f;
        for (int k = 0; k < S; ++k) s += part[(long)k * n + i];
        out[i] = s;
    }
}

// ---------------------------------------------------------------------------
// conversions
// ---------------------------------------------------------------------------
__global__ __launch_bounds__(256) void cvt_ppr(
    const float* __restrict__ ppr, ushort* __restrict__ pprb,
    ushort* __restrict__ ppr2b)
{
    int c = blockIdx.x * 256 + threadIdx.x;
    int r = blockIdx.y;
    if (c >= 8000) return;
    float v = (r < 2000) ? ppr[(long)r * 8000 + c] : 0.f;
    ushort u = bf16_rne(v);
    pprb[(long)r * 8000 + c] = u;
    if (c < 2048) ppr2b[(long)r * 2048 + c] = (c < 2000) ? u : (ushort)0;
}

__global__ __launch_bounds__(256) void transpose_cvt(
    const float* __restrict__ in, ushort* __restrict__ out,
    int R, int C, int Rpad)
{
    __shared__ float t[32][33];
    int c0 = blockIdx.x * 32, r0 = blockIdx.y * 32;
    int tx = threadIdx.x & 31, ty = threadIdx.x >> 5;
#pragma unroll
    for (int k = 0; k < 32; k += 8) {
        int r = r0 + ty + k;
        t[ty + k][tx] = (r < R) ? in[(long)r * C + c0 + tx] : 0.f;
    }
    __syncthreads();
#pragma unroll
    for (int k = 0; k < 32; k += 8) {
        int c = c0 + ty + k;
        out[(long)c * Rpad + r0 + tx] = bf16_rne(t[tx][ty + k]);
    }
}

__global__ __launch_bounds__(256) void cvt_plain(
    const float* __restrict__ in, ushort* __restrict__ out, long n)
{
    long stride = (long)gridDim.x * 256;
    for (long i = (long)blockIdx.x * 256 + threadIdx.x; i < n; i += stride)
        out[i] = bf16_rne(in[i]);
}

// in fp32 [R,C] (ldin) -> out bf16 [grid.x rows, 2C] = [hi | lo], pads zero.
__global__ __launch_bounds__(256) void split_rows(
    const float* __restrict__ in, ushort* __restrict__ out,
    int R, int C, int ldin)
{
    int r = blockIdx.x, t = threadIdx.x;
    long ro = (long)r * (2 * C);
    for (int c = t; c < C; c += 256) {
        float v = (r < R) ? in[(long)r * ldin + c] : 0.f;
        ushort h = bf16_rne(v);
        ushort l = bf16_rne(v - bf16_f32(h));
        out[ro + c] = h;
        out[ro + C + c] = l;
    }
}

// pack all 10 weight sections in one launch: out[n, K*dup] = bf16(W[n, k%K])
__global__ __launch_bounds__(256) void pack_weights(
    const float* __restrict__ Wr0, const float* __restrict__ Wl0,
    const float* __restrict__ Wr1, const float* __restrict__ Wl1,
    const float* __restrict__ W1,  const float* __restrict__ W2,
    const float* __restrict__ Wa,  const float* __restrict__ Wb,
    const float* __restrict__ Wp1, const float* __restrict__ Wp2,
    ushort* __restrict__ base)
{
    const float* src; ushort* dst; int N, Kd, dup;
    switch (blockIdx.y) {
        case 0: src = Wr0; dst = base + U_WRB;           N = 256; Kd = 512; dup = 1; break;
        case 1: src = Wl0; dst = base + U_WL0D;          N = 256; Kd = 512; dup = 2; break;
        case 2: src = Wr1; dst = base + U_WR1D;          N = 256; Kd = 256; dup = 2; break;
        case 3: src = Wl1; dst = base + U_WL1D;          N = 256; Kd = 256; dup = 2; break;
        case 4: src = W1;  dst = base + U_BD;            N = 256; Kd = 256; dup = 2; break;
        case 5: src = W2;  dst = base + U_BD + 131072;   N = 256; Kd = 256; dup = 2; break;
        case 6: src = Wa;  dst = base + U_WAD;           N = 512; Kd = 512; dup = 2; break;
        case 7: src = Wb;  dst = base + U_WBD;           N = 256; Kd = 512; dup = 2; break;
        case 8: src = Wp1; dst = base + U_WP1D;          N = 256; Kd = 256; dup = 2; break;
        default:src = Wp2; dst = base + U_WP2D;          N = 256; Kd = 256; dup = 2; break;
    }
    long total = (long)N * Kd * dup;
    int kd = Kd * dup;
    for (long idx = (long)blockIdx.x * 256 + threadIdx.x; idx < total;
         idx += (long)gridDim.x * 256) {
        int n = (int)(idx / kd), rem = (int)(idx % kd), k = rem % Kd;
        dst[(long)n * kd + rem] = bf16_rne(src[(long)n * Kd + k]);
    }
}

// ---------------------------------------------------------------------------
// CSR build + gather-mean (replaces fp32 atomic scatter)
// ---------------------------------------------------------------------------
__global__ __launch_bounds__(256) void hist_i(
    const int* __restrict__ dst, int* __restrict__ cnt, int E)
{
    int e = blockIdx.x * 256 + threadIdx.x;
    if (e < E) atomicAdd(&cnt[dst[e]], 1);
}

// single block, n <= 8192: exclusive scan of cnt -> off and cur.
__global__ __launch_bounds__(256) void scan_excl(
    const int* __restrict__ cnt, int* __restrict__ off, int* __restrict__ cur, int n)
{
    __shared__ int tot[256];
    int t = threadIdx.x;
    int base = t * 32;
    int loc[32];
    int s = 0;
#pragma unroll
    for (int j = 0; j < 32; ++j) {
        int i = base + j;
        int v = (i < n) ? cnt[i] : 0;
        loc[j] = s; s += v;
    }
    tot[t] = s;
    __syncthreads();
    for (int d = 1; d < 256; d <<= 1) {
        int v = (t >= d) ? tot[t - d] : 0;
        __syncthreads();
        tot[t] += v;
        __syncthreads();
    }
    int b = (t > 0) ? tot[t - 1] : 0;
#pragma unroll
    for (int j = 0; j < 32; ++j) {
        int i = base + j;
        if (i < n) { off[i] = b + loc[j]; cur[i] = b + loc[j]; }
    }
}

__global__ __launch_bounds__(256) void fill_csr(
    const int* __restrict__ src, const int* __restrict__ dst,
    int* __restrict__ cur, int* __restrict__ eid, int E)
{
    int e = blockIdx.x * 256 + threadIdx.x;
    if (e < E) {
        int p = atomicAdd(&cur[dst[e]], 1);
        eid[p] = src[e];
    }
}

// one block per dst row: mean of gathered h rows, write bf16 [hi|lo] split.
// D = 256 or 512; out row d = [hi(D) | lo(D)], ldout = 2D. Pads (d>=n) zero.
__global__ __launch_bounds__(256) void csr_agg_split(
    const float* __restrict__ h, const int* __restrict__ eid,
    const int* __restrict__ off, const int* __restrict__ cnt,
    ushort* __restrict__ out, int n, int D, int ldout)
{
    int d = blockIdx.x, t = threadIdx.x;
    float a0 = 0.f, a1 = 0.f;
    if (d < n) {
        int base = off[d], k = cnt[d];
        for (int j = 0; j < k; ++j) {
            const float* hr = h + (long)eid[base + j] * D;
            a0 += hr[t];
            if (D == 512) a1 += hr[t + 256];
        }
        float inv = 1.f / fmaxf((float)k, 1.f);
        a0 *= inv; a1 *= inv;
    }
    long ro = (long)d * ldout;
    ushort h0 = bf16_rne(a0);
    ushort l0 = bf16_rne(a0 - bf16_f32(h0));
    out[ro + t] = h0;
    out[ro + D + t] = l0;
    if (D == 512) {
        ushort h1 = bf16_rne(a1);
        ushort l1 = bf16_rne(a1 - bf16_f32(h1));
        out[ro + 256 + t] = h1;
        out[ro + D + 256 + t] = l1;
    }
}

// ------------------------- row-wise kernels (D=256) ------------------------
__global__ __launch_bounds__(256) void logsoftmax_rows(float* __restrict__ h, int D)
{
    __shared__ float red[256];
    int i = blockIdx.x, t = threadIdx.x;
    float v = h[(long)i * D + t];
    red[t] = v;
    __syncthreads();
    for (int s = 128; s > 0; s >>= 1) {
        if (t < s) red[t] = fmaxf(red[t], red[t + s]);
        __syncthreads();
    }
    float m = red[0];
    __syncthreads();
    float e = expf(v - m);
    red[t] = e;
    __syncthreads();
    for (int s = 128; s > 0; s >>= 1) {
        if (t < s) red[t] += red[t + s];
        __syncthreads();
    }
    float lse = m + logf(red[0]);
    h[(long)i * D + t] = v - lse;
}

__global__ __launch_bounds__(256) void l2n_rows(
    const float* __restrict__ in, float* __restrict__ out, int D)
{
    __shared__ float red[256];
    int i = blockIdx.x, t = threadIdx.x;
    float v = in[(long)i * D + t];
    red[t] = v * v;
    __syncthreads();
    for (int s = 128; s > 0; s >>= 1) {
        if (t < s) red[t] += red[t + s];
        __syncthreads();
    }
    float nrm = fmaxf(sqrtf(red[0]), 1e-12f);
    out[(long)i * D + t] = v / nrm;
}

__global__ __launch_bounds__(256) void div_rows(
    const float* __restrict__ o1, const float* __restrict__ o2,
    float* __restrict__ loss, int ld, int D, float scale)
{
    __shared__ float r1[256];
    __shared__ float r2[256];
    int i = blockIdx.x, t = threadIdx.x;
    float a = o1[(long)i * ld + t], b = o2[(long)i * ld + t];
    r1[t] = a * a;
    r2[t] = b * b;
    __syncthreads();
    for (int s = 128; s > 0; s >>= 1) {
        if (t < s) { r1[t] += r1[t + s]; r2[t] += r2[t + s]; }
        __syncthreads();
    }
    float na = fmaxf(sqrtf(r1[0]), 1e-12f);
    float nb = fmaxf(sqrtf(r2[0]), 1e-12f);
    __syncthreads();
    float d = a / na - b / nb;
    r1[t] = d * d;
    __syncthreads();
    for (int s = 128; s > 0; s >>= 1) {
        if (t < s) r1[t] += r1[t + s];
        __syncthreads();
    }
    if (t == 0) atomicAdd(loss, r1[0] * scale);
}

__global__ __launch_bounds__(256) void clf_kernel(
    const float* __restrict__ p, const float* __restrict__ Wc1,
    const float* __restrict__ bc1, const float* __restrict__ Wc2,
    const float* __restrict__ bc2, float* __restrict__ out, int col, int D)
{
    __shared__ float v[256];
    __shared__ float hsum[32];
    int i = blockIdx.x, t = threadIdx.x;
    v[t] = p[(long)i * D + t];
    __syncthreads();
    if (t < 32) {
        float s = bc1[t];
        const float* w = Wc1 + (long)t * D;
        for (int k = 0; k < D; ++k) s += v[k] * w[k];
        s = fmaxf(s, 0.f);
        hsum[t] = s * Wc2[t];
    }
    __syncthreads();
    if (t == 0) {
        float s = bc2[0];
        for (int k = 0; k < 32; ++k) s += hsum[k];
        out[(long)i * 2 + col] = s;
    }
}

__global__ void write_loss(const float* __restrict__ loss, float* __restrict__ out)
{
    out[0] = loss[0];
}

// ---------------------------------------------------------------------------
extern "C" void kernel_launch(void* const* d_in, const int* in_sizes, int n_in,
                              void* d_out, int out_size, void* d_ws, size_t ws_size,
                              hipStream_t stream)
{
    constexpr int N1 = 8000, N2 = 2000, IN = 512, HID = 256;

    const float* x   = (const float*)d_in[0];
    const float* ppr = (const float*)d_in[1];
    const int* src0  = (const int*)d_in[2];
    const int* dst0  = (const int*)d_in[3];
    const int* src1  = (const int*)d_in[4];
    const int* dst1  = (const int*)d_in[5];
    const float* Wl0 = (const float*)d_in[8];
    const float* bl0 = (const float*)d_in[9];
    const float* Wr0 = (const float*)d_in[10];
    const float* Wl1 = (const float*)d_in[11];
    const float* bl1 = (const float*)d_in[12];
    const float* Wr1 = (const float*)d_in[13];
    const float* Wa  = (const float*)d_in[14];
    const float* ba  = (const float*)d_in[15];
    const float* Wb  = (const float*)d_in[16];
    const float* bb  = (const float*)d_in[17];
    const float* W1  = (const float*)d_in[18];
    const float* W2  = (const float*)d_in[19];
    const float* Wp1 = (const float*)d_in[20];
    const float* bp1 = (const float*)d_in[21];
    const float* Wp2 = (const float*)d_in[22];
    const float* bp2 = (const float*)d_in[23];
    const float* Wc1 = (const float*)d_in[24];
    const float* bc1 = (const float*)d_in[25];
    const float* Wc2 = (const float*)d_in[26];
    const float* bc2 = (const float*)d_in[27];

    const int E0 = in_sizes[2];
    const int E1 = in_sizes[4];

    float* out = (float*)d_out;              // [2000,2] logits + [1] loss
    float* ws  = (float*)d_ws;
    int*   iws = (int*)d_ws;
    ushort* uws = (ushort*)((char*)d_ws + FEND * sizeof(float));

    auto cdiv = [](int a, int b) { return (a + b - 1) / b; };

    // zero: histograms + loss (40 KB)
    hipMemsetAsync(ws, 0, (size_t)ZEND * sizeof(float), stream);

    // ---- input conversions (independent) ----
    pack_weights<<<dim3(2048, 10), 256, 0, stream>>>(
        Wr0, Wl0, Wr1, Wl1, W1, W2, Wa, Wb, Wp1, Wp2, uws);
    cvt_ppr<<<dim3(32, 2048), 256, 0, stream>>>(ppr, uws + U_PPRB, uws + U_PPR2B);
    transpose_cvt<<<dim3(16, 250), 256, 0, stream>>>(x, uws + U_XTB, N1, IN, 8000);
    cvt_plain<<<4096, 256, 0, stream>>>(x, uws + U_XB, (long)8064 * 512);

    // ---- SAGE layer 0: CSR aggregate + MFMA ----
    hist_i<<<cdiv(E0, 256), 256, 0, stream>>>(dst0, iws + ZCNT0, E0);
    scan_excl<<<1, 256, 0, stream>>>(iws + ZCNT0, iws + OFF0, iws + CUR0, N1);
    fill_csr<<<cdiv(E0, 256), 256, 0, stream>>>(src0, dst0, iws + CUR0, iws + EID0, E0);
    csr_agg_split<<<8064, 256, 0, stream>>>(
        x, iws + EID0, iws + OFF0, iws + ZCNT0, uws + U_A0B, N1, IN, 1024);
    // H1 = relu(xb @ Wr0^T  +  [agg_hi|agg_lo] @ [Wl0|Wl0]^T + bl0)
    mfma_bt<<<dim3(2, 63), 256, 0, stream>>>(
        uws + U_XB, uws + U_WRB, ws + H1, 512, 512, 512, 256, nullptr, 0);
    mfma_bt<<<dim3(2, 63), 256, 0, stream>>>(
        uws + U_A0B, uws + U_WL0D, ws + H1, 1024, 1024, 1024, 256, bl0, 3);

    // ---- SAGE layer 1 ----
    hist_i<<<cdiv(E1, 256), 256, 0, stream>>>(dst1, iws + ZCNT1, E1);
    scan_excl<<<1, 256, 0, stream>>>(iws + ZCNT1, iws + OFF1, iws + CUR1, N2);
    fill_csr<<<cdiv(E1, 256), 256, 0, stream>>>(src1, dst1, iws + CUR1, iws + EID1, E1);
    csr_agg_split<<<2048, 256, 0, stream>>>(
        ws + H1, iws + EID1, iws + OFF1, iws + ZCNT1, uws + U_SCR + 1048576, N2, HID, 512);
    split_rows<<<2048, 256, 0, stream>>>(ws + H1, uws + U_SCR, N2, HID, HID);
    mfma_bt<<<dim3(2, 16), 256, 0, stream>>>(
        uws + U_SCR, uws + U_WR1D, ws + H2, 512, 512, 512, 256, nullptr, 0);
    mfma_bt<<<dim3(2, 16), 256, 0, stream>>>(
        uws + U_SCR + 1048576, uws + U_WL1D, ws + H2, 512, 512, 512, 256, bl1, 1);
    logsoftmax_rows<<<N2, 256, 0, stream>>>(ws + H2, HID);

    // ---- divergence loss: DIVC = [e_hi|e_lo] @ [[W1|W1];[W2|W2]]^T ----
    split_rows<<<2048, 256, 0, stream>>>(ws + H2, uws + U_SCR, N2, HID, HID);
    mfma_bt<<<dim3(4, 16), 256, 0, stream>>>(
        uws + U_SCR, uws + U_BD, ws + DIVC, 512, 512, 512, 512, nullptr, 0);
    div_rows<<<N2, 256, 0, stream>>>(ws + DIVC, ws + DIVC + 256, ws + ZLOSS,
                                     512, HID, 1.0f / N2);

    // ---- PPR branch ----
    // xp1 = pprb @ xT^T, K=8000, split-K=5 (320 blocks)
    mfma_bt_sk<<<dim3(4, 16, 5), 256, 0, stream>>>(
        uws + U_PPRB, uws + U_XTB, ws + PART, 8000, 1600, 8000, 8000, 512);
    reduce_parts<<<4096, 256, 0, stream>>>(ws + PART, ws + XP1, 1048576L, 5);
    // xpa = relu([xp1_hi|xp1_lo] @ [Wa|Wa]^T + ba)
    split_rows<<<2048, 256, 0, stream>>>(ws + XP1, uws + U_XPS, 2048, IN, IN);
    mfma_bt<<<dim3(4, 16), 256, 0, stream>>>(
        uws + U_XPS, uws + U_WAD, ws + XPA, 1024, 1024, 1024, 512, ba, 2);
    transpose_cvt<<<dim3(16, 64), 256, 0, stream>>>(ws + XPA, uws + U_XPATB, N2, IN, 2048);
    // xp2 = ppr2b @ xpaT^T, K=2048, split-K=2
    mfma_bt_sk<<<dim3(4, 16, 2), 256, 0, stream>>>(
        uws + U_PPR2B, uws + U_XPATB, ws + PART, 2048, 1024, 2048, 2048, 512);
    reduce_parts<<<4096, 256, 0, stream>>>(ws + PART, ws + XP2, 1048576L, 2);
    // xpb = [xp2_hi|xp2_lo] @ [Wb|Wb]^T + bb
    split_rows<<<2048, 256, 0, stream>>>(ws + XP2, uws + U_XPS, 2048, IN, IN);
    mfma_bt<<<dim3(2, 16), 256, 0, stream>>>(
        uws + U_XPS, uws + U_WBD, ws + XPBF, 1024, 1024, 1024, 256, bb, 0);

    // ---- branch 1: g1 = l2n(ebds) -> proj -> clf -> out[:,0] ----
    l2n_rows<<<N2, 256, 0, stream>>>(ws + H2, ws + GB, HID);
    split_rows<<<2048, 256, 0, stream>>>(ws + GB, uws + U_SCR, N2, HID, HID);
    mfma_bt<<<dim3(2, 16), 256, 0, stream>>>(
        uws + U_SCR, uws + U_WP1D, ws + TB, 512, 512, 512, 256, bp1, 2);
    split_rows<<<2048, 256, 0, stream>>>(ws + TB, uws + U_SCR, N2, HID, HID);
    mfma_bt<<<dim3(2, 16), 256, 0, stream>>>(
        uws + U_SCR, uws + U_WP2D, ws + PB, 512, 512, 512, 256, bp2, 0);
    clf_kernel<<<N2, 256, 0, stream>>>(ws + PB, Wc1, bc1, Wc2, bc2, out, 0, HID);

    // ---- branch 2: g2 = l2n(xpb) -> proj -> clf -> out[:,1] ----
    l2n_rows<<<N2, 256, 0, stream>>>(ws + XPBF, ws + GB, HID);
    split_rows<<<2048, 256, 0, stream>>>(ws + GB, uws + U_SCR, N2, HID, HID);
    mfma_bt<<<dim3(2, 16), 256, 0, stream>>>(
        uws + U_SCR, uws + U_WP1D, ws + TB, 512, 512, 512, 256, bp1, 2);
    split_rows<<<2048, 256, 0, stream>>>(ws + TB, uws + U_SCR, N2, HID, HID);
    mfma_bt<<<dim3(2, 16), 256, 0, stream>>>(
        uws + U_SCR, uws + U_WP2D, ws + PB, 512, 512, 512, 256, bp2, 0);
    clf_kernel<<<N2, 256, 0, stream>>>(ws + PB, Wc1, bc1, Wc2, bc2, out, 1, HID);

    write_loss<<<1, 1, 0, stream>>>(ws + ZLOSS, out + (long)N2 * 2);
}

// Round 2
// 846.129 us; speedup vs baseline: 1.8334x; 1.1233x over previous
//
#include <hip/hip_runtime.h>

// ============================================================================
// train_model_27925877358676 — round 6:
//  (1) mfma128: BK=128 tile (64KB LDS, XOR-swizzle via pre-swizzled global
//      source + swizzled ds_read) -> 4x fewer vmcnt-drain stalls per GEMM.
//  (2) K-fusion: H1 = [x|agg_hi|agg_lo]@[Wr0|Wl0|Wl0]^T (K=1536, 1 GEMM,
//      no beta RMW); H2 = [h1_hi|h1_lo|agg_hi|agg_lo]@[Wr1|Wr1|Wl1|Wl1]^T.
//  (3) Epilogue-fused bf16 hi/lo split writes (split_rows deleted);
//      logsoftmax+l2n+split fused; reduce_parts writes splits directly.
//  (4) Branch tails stacked: one proj1/proj2/clf over [4096] rows.
// ws ≈ 143.7 MB (fp32 42.6 + bf16 101.1) <= round-5's 145.8 MB.
// ============================================================================

typedef unsigned short ushort;
typedef __attribute__((ext_vector_type(8))) short short8;     // 8 bf16
typedef __attribute__((ext_vector_type(4))) float float4v;    // 4 fp32 acc
typedef __attribute__((ext_vector_type(4))) float f32x4;
typedef __attribute__((ext_vector_type(4))) unsigned short us4;

__device__ __forceinline__ ushort bf16_rne(float v) {
    unsigned u = __float_as_uint(v);
    u += 0x7fffu + ((u >> 16) & 1u);
    return (ushort)(u >> 16);
}
__device__ __forceinline__ float bf16_f32(ushort h) {
    return __uint_as_float((unsigned)h << 16);
}

// ---------------- workspace layout ----------------
// fp32 region (float/int offsets)
constexpr long ZCNT0 = 0;          // int[8000] (zeroed)
constexpr long ZCNT1 = 8000;       // int[2000] (zeroed)
constexpr long ZLOSS = 10000;      // float (zeroed)
constexpr long ZEND  = 10240;
constexpr long OFF0  = 10240;
constexpr long CUR0  = 18240;
constexpr long OFF1  = 26240;
constexpr long CUR1  = 28240;
constexpr long EID0  = 30240;      // int[128000]
constexpr long EID1  = 158240;     // int[32000]
constexpr long H1F   = 190240;     // f[8064*256]
constexpr long H2F   = 2254624;    // f[2048*256]
constexpr long DIVCF = 2778912;    // f[2048*512]
constexpr long XPBF  = 3827488;    // f[2048*256]
constexpr long PB2   = 4351776;    // f[4096*256]
constexpr long PART  = 5400352;    // f[5*2048*512]
constexpr long FEND  = 10643232;
// bf16 region (ushort offsets from uws)
constexpr long U_PPRB  = 0;         // [2048][8000]
constexpr long U_PPR2B = 16384000;  // [2048][2048]
constexpr long U_XTB   = 20578304;  // [512][8000]
constexpr long U_XPATB = 24674304;  // [512][2048]
constexpr long U_A0    = 25722880;  // [8064][1536] = [x | agg_hi | agg_lo]
constexpr long U_A1    = 38109184;  // [2048][1024] = [h1_hi|h1_lo|agg_hi|agg_lo]
constexpr long U_ESPL  = 40206336;  // [2048][512]  = [e_hi|e_lo]
constexpr long U_XPS   = 41254912;  // [2048][1024] = [hi|lo]
constexpr long U_XPAB  = 43352064;  // [2048][512] plain bf16 xpa
constexpr long U_SPLT  = 44400640;  // [4096][512]  = [g_hi|g_lo] stacked
constexpr long U_TSPL  = 46497792;  // [4096][512]  = [t_hi|t_lo]
constexpr long U_WC0   = 48594944;  // [256][1536] [Wr0|Wl0|Wl0]
constexpr long U_WC1   = 48988160;  // [256][1024] [Wr1|Wr1|Wl1|Wl1]
constexpr long U_BD    = 49250304;  // [512][512]  [[W1|W1];[W2|W2]]
constexpr long U_WAD   = 49512448;  // [512][1024] [Wa|Wa]
constexpr long U_WBD   = 50036736;  // [256][1024] [Wb|Wb]
constexpr long U_WP1D  = 50298880;  // [256][512]  [Wp1|Wp1]
constexpr long U_WP2D  = 50429952;  // [256][512]  [Wp2|Wp2]
// end 50561024 ushorts

// ---------------------------------------------------------------------------
// mfma128: C[M,N] = op(A[M,K] @ B[N,K]^T), bf16 in. BK=128, 128x128 tile,
// XOR-swizzled LDS (slot ^= row&15) with pre-swizzled global source so the
// global_load_lds destination stays linear. K % 128 == 0, M/N padded exact.
// Cf (fp32, nullable): v. Cs (bf16, nullable): rows < msplit get either
// split [hi@col | lo@col+nsplit] (flags&2) or plain bf16 (else).
// flags: bit0 relu, bit1 split-mode.
// ---------------------------------------------------------------------------
__global__ __launch_bounds__(256) void mfma128(
    const ushort* __restrict__ A, const ushort* __restrict__ B,
    float* __restrict__ Cf, ushort* __restrict__ Cs,
    const float* __restrict__ bias, int K, int lda, int ldb, int ldc,
    int ldso, int nsplit, int msplit, int flags)
{
    __shared__ ushort As[128 * 128];
    __shared__ ushort Bs[128 * 128];
    const int tid = threadIdx.x;
    const int lane = tid & 63, wave = tid >> 6;
    const int wm = (wave >> 1) * 64, wn = (wave & 1) * 64;
    const int lr = lane & 15, quad = lane >> 4;
    const int bm = blockIdx.y * 128, bn = blockIdx.x * 128;

    float4v acc[4][4] = {{{0.f, 0.f, 0.f, 0.f}}};

    for (int k0 = 0; k0 < K; k0 += 128) {
#pragma unroll
        for (int issue = 0; issue < 8; ++issue) {
            int c = issue * 256 + tid;           // 0..2047
            int r = c >> 4, p = c & 15;
            int kk = (p ^ (r & 15)) * 8;         // pre-swizzled source column
            const ushort* ga = A + (long)(bm + r) * lda + k0 + kk;
            const ushort* gb = B + (long)(bn + r) * ldb + k0 + kk;
            __builtin_amdgcn_global_load_lds(
                (const __attribute__((address_space(1))) unsigned int*)ga,
                (__attribute__((address_space(3))) unsigned int*)&As[c * 8], 16, 0, 0);
            __builtin_amdgcn_global_load_lds(
                (const __attribute__((address_space(1))) unsigned int*)gb,
                (__attribute__((address_space(3))) unsigned int*)&Bs[c * 8], 16, 0, 0);
        }
        __syncthreads();

#pragma unroll
        for (int s = 0; s < 4; ++s) {
            short8 af[4], bf[4];
#pragma unroll
            for (int i = 0; i < 4; ++i) {
                int ra = wm + i * 16 + lr;
                af[i] = *(const short8*)&As[ra * 128 + (((s * 4 + quad) ^ (ra & 15)) * 8)];
                int rb = wn + i * 16 + lr;
                bf[i] = *(const short8*)&Bs[rb * 128 + (((s * 4 + quad) ^ (rb & 15)) * 8)];
            }
#pragma unroll
            for (int i = 0; i < 4; ++i)
#pragma unroll
                for (int j = 0; j < 4; ++j)
                    acc[i][j] = __builtin_amdgcn_mfma_f32_16x16x32_bf16(
                        af[i], bf[j], acc[i][j], 0, 0, 0);
        }
        __syncthreads();
    }

#pragma unroll
    for (int i = 0; i < 4; ++i) {
        int row0 = bm + wm + i * 16 + quad * 4;
#pragma unroll
        for (int j = 0; j < 4; ++j) {
            int col = bn + wn + j * 16 + lr;
            float bv = bias ? bias[col] : 0.f;
#pragma unroll
            for (int r = 0; r < 4; ++r) {
                int row = row0 + r;
                float v = acc[i][j][r] + bv;
                if (flags & 1) v = fmaxf(v, 0.f);
                if (Cf) Cf[(long)row * ldc + col] = v;
                if (Cs && row < msplit) {
                    if (flags & 2) {
                        ushort h = bf16_rne(v);
                        Cs[(long)row * ldso + col] = h;
                        Cs[(long)row * ldso + nsplit + col] = bf16_rne(v - bf16_f32(h));
                    } else {
                        Cs[(long)row * ldso + col] = bf16_rne(v);
                    }
                }
            }
        }
    }
}

// ---------------------------------------------------------------------------
// split-K MFMA (BK=32, proven m97 layout) for xp1 (K=8000) / xp2 (K=2048).
// ---------------------------------------------------------------------------
__global__ __launch_bounds__(256) void mfma_bt_sk(
    const ushort* __restrict__ A, const ushort* __restrict__ B,
    float* __restrict__ Cp, int K, int kchunk, int lda, int ldb, int ldc)
{
    __shared__ ushort As[128 * 32];
    __shared__ ushort Bs[128 * 32];
    const int tid = threadIdx.x;
    const int lane = tid & 63, wave = tid >> 6;
    const int wm = (wave >> 1) * 64, wn = (wave & 1) * 64;
    const int lr = lane & 15, quad = lane >> 4;
    const int bm = blockIdx.y * 128, bn = blockIdx.x * 128;
    const int kbeg = blockIdx.z * kchunk;
    const int kend = (kbeg + kchunk < K) ? (kbeg + kchunk) : K;
    float* C = Cp + (long)blockIdx.z * (long)(gridDim.x * 128) * (long)(gridDim.y * 128);

    float4v acc[4][4] = {{{0.f, 0.f, 0.f, 0.f}}};

    for (int k0 = kbeg; k0 < kend; k0 += 32) {
#pragma unroll
        for (int issue = 0; issue < 2; ++issue) {
            int c = issue * 256 + tid;
            int r = c >> 2, p = (c & 3) * 8;
            const ushort* ga = A + (long)(bm + r) * lda + k0 + p;
            const ushort* gb = B + (long)(bn + r) * ldb + k0 + p;
            __builtin_amdgcn_global_load_lds(
                (const __attribute__((address_space(1))) unsigned int*)ga,
                (__attribute__((address_space(3))) unsigned int*)&As[c * 8], 16, 0, 0);
            __builtin_amdgcn_global_load_lds(
                (const __attribute__((address_space(1))) unsigned int*)gb,
                (__attribute__((address_space(3))) unsigned int*)&Bs[c * 8], 16, 0, 0);
        }
        __syncthreads();

        short8 af[4], bf[4];
#pragma unroll
        for (int i = 0; i < 4; ++i) {
            af[i] = *(const short8*)&As[(wm + i * 16 + lr) * 32 + quad * 8];
            bf[i] = *(const short8*)&Bs[(wn + i * 16 + lr) * 32 + quad * 8];
        }
#pragma unroll
        for (int i = 0; i < 4; ++i)
#pragma unroll
            for (int j = 0; j < 4; ++j)
                acc[i][j] = __builtin_amdgcn_mfma_f32_16x16x32_bf16(
                    af[i], bf[j], acc[i][j], 0, 0, 0);
        __syncthreads();
    }

#pragma unroll
    for (int i = 0; i < 4; ++i) {
        int row0 = bm + wm + i * 16 + quad * 4;
#pragma unroll
        for (int j = 0; j < 4; ++j) {
            int col = bn + wn + j * 16 + lr;
#pragma unroll
            for (int r = 0; r < 4; ++r)
                C[(long)(row0 + r) * ldc + col] = acc[i][j][r];
        }
    }
}

// sum S partial slabs of [2048][512] -> bf16 hi/lo split [2048][1024]
__global__ __launch_bounds__(256) void reduce_split(
    const float* __restrict__ part, ushort* __restrict__ outs, long n, int S)
{
    long i = (long)blockIdx.x * 256 + threadIdx.x;
    if (i >= n) return;
    float s = 0.f;
    for (int k = 0; k < S; ++k) s += part[(long)k * n + i];
    int r = (int)(i >> 9), c = (int)(i & 511);
    ushort h = bf16_rne(s);
    outs[(long)r * 1024 + c] = h;
    outs[(long)r * 1024 + 512 + c] = bf16_rne(s - bf16_f32(h));
}

// ---------------------------------------------------------------------------
// conversions
// ---------------------------------------------------------------------------
__global__ __launch_bounds__(256) void cvt_ppr(
    const float* __restrict__ ppr, ushort* __restrict__ pprb,
    ushort* __restrict__ ppr2b)
{
    int r = blockIdx.x;                 // 0..2047
    bool live = r < 2000;
    const float* row = ppr + (long)r * 8000;
    for (int c = threadIdx.x * 4; c < 8000; c += 1024) {
        f32x4 v = {0.f, 0.f, 0.f, 0.f};
        if (live) v = *(const f32x4*)(row + c);
        us4 u;
        u[0] = bf16_rne(v[0]); u[1] = bf16_rne(v[1]);
        u[2] = bf16_rne(v[2]); u[3] = bf16_rne(v[3]);
        *(us4*)&pprb[(long)r * 8000 + c] = u;
        if (c < 2048) {
            us4 w = u;
            if (c >= 2000) { w[0] = 0; w[1] = 0; w[2] = 0; w[3] = 0; }
            *(us4*)&ppr2b[(long)r * 2048 + c] = w;
        }
    }
}

// fp32 [R,C] -> bf16 [C][Rpad] transpose (rows >= R contribute 0)
__global__ __launch_bounds__(256) void transpose_cvt(
    const float* __restrict__ in, ushort* __restrict__ out,
    int R, int C, int Rpad)
{
    __shared__ float t[32][33];
    int c0 = blockIdx.x * 32, r0 = blockIdx.y * 32;
    int tx = threadIdx.x & 31, ty = threadIdx.x >> 5;
#pragma unroll
    for (int k = 0; k < 32; k += 8) {
        int r = r0 + ty + k;
        t[ty + k][tx] = (r < R) ? in[(long)r * C + c0 + tx] : 0.f;
    }
    __syncthreads();
#pragma unroll
    for (int k = 0; k < 32; k += 8) {
        int c = c0 + ty + k;
        out[(long)c * Rpad + r0 + tx] = bf16_rne(t[tx][ty + k]);
    }
}

// bf16 [R][C] -> bf16 [C][R]
__global__ __launch_bounds__(256) void transpose_bf16(
    const ushort* __restrict__ in, ushort* __restrict__ out, int R, int C)
{
    __shared__ ushort t[32][33];
    int c0 = blockIdx.x * 32, r0 = blockIdx.y * 32;
    int tx = threadIdx.x & 31, ty = threadIdx.x >> 5;
#pragma unroll
    for (int k = 0; k < 32; k += 8)
        t[ty + k][tx] = in[(long)(r0 + ty + k) * C + c0 + tx];
    __syncthreads();
#pragma unroll
    for (int k = 0; k < 32; k += 8)
        out[(long)(c0 + ty + k) * R + r0 + tx] = t[tx][ty + k];
}

// x rows 0..8063 -> A0 cols 0..511 (ld 1536)
__global__ __launch_bounds__(256) void cvt_x_a0(
    const float* __restrict__ x, ushort* __restrict__ a0)
{
    int r = blockIdx.x;
    for (int c = threadIdx.x; c < 512; c += 256)
        a0[(long)r * 1536 + c] = bf16_rne(x[(long)r * 512 + c]);
}

// pack weights: 8 sections, each [srcA dup dA | srcB dup dB]
__global__ __launch_bounds__(256) void pack_weights(
    const float* __restrict__ Wr0, const float* __restrict__ Wl0,
    const float* __restrict__ Wr1, const float* __restrict__ Wl1,
    const float* __restrict__ W1,  const float* __restrict__ W2,
    const float* __restrict__ Wa,  const float* __restrict__ Wb,
    const float* __restrict__ Wp1, const float* __restrict__ Wp2,
    ushort* __restrict__ base)
{
    const float *sa, *sb; ushort* dst; int N, KA, dA, KB, dB;
    switch (blockIdx.y) {
        case 0: sa = Wr0; KA = 512; dA = 1; sb = Wl0; KB = 512; dB = 2;
                dst = base + U_WC0; N = 256; break;
        case 1: sa = Wr1; KA = 256; dA = 2; sb = Wl1; KB = 256; dB = 2;
                dst = base + U_WC1; N = 256; break;
        case 2: sa = W1;  KA = 256; dA = 2; sb = nullptr; KB = 0; dB = 0;
                dst = base + U_BD; N = 256; break;
        case 3: sa = W2;  KA = 256; dA = 2; sb = nullptr; KB = 0; dB = 0;
                dst = base + U_BD + 131072; N = 256; break;
        case 4: sa = Wa;  KA = 512; dA = 2; sb = nullptr; KB = 0; dB = 0;
                dst = base + U_WAD; N = 512; break;
        case 5: sa = Wb;  KA = 512; dA = 2; sb = nullptr; KB = 0; dB = 0;
                dst = base + U_WBD; N = 256; break;
        case 6: sa = Wp1; KA = 256; dA = 2; sb = nullptr; KB = 0; dB = 0;
                dst = base + U_WP1D; N = 256; break;
        default: sa = Wp2; KA = 256; dA = 2; sb = nullptr; KB = 0; dB = 0;
                dst = base + U_WP2D; N = 256; break;
    }
    int kd = KA * dA + KB * dB;
    long total = (long)N * kd;
    for (long idx = (long)blockIdx.x * 256 + threadIdx.x; idx < total;
         idx += (long)gridDim.x * 256) {
        int n = (int)(idx / kd), rem = (int)(idx % kd);
        float v;
        if (rem < KA * dA) v = sa[(long)n * KA + rem % KA];
        else               v = sb[(long)n * KB + (rem - KA * dA) % KB];
        dst[idx] = bf16_rne(v);
    }
}

// ---------------------------------------------------------------------------
// CSR build + gather-mean
// ---------------------------------------------------------------------------
__global__ __launch_bounds__(256) void hist_i(
    const int* __restrict__ dst, int* __restrict__ cnt, int E)
{
    int e = blockIdx.x * 256 + threadIdx.x;
    if (e < E) atomicAdd(&cnt[dst[e]], 1);
}

__global__ __launch_bounds__(256) void scan_excl(
    const int* __restrict__ cnt, int* __restrict__ off, int* __restrict__ cur, int n)
{
    __shared__ int tot[256];
    int t = threadIdx.x;
    int base = t * 32;
    int loc[32];
    int s = 0;
#pragma unroll
    for (int j = 0; j < 32; ++j) {
        int i = base + j;
        int v = (i < n) ? cnt[i] : 0;
        loc[j] = s; s += v;
    }
    tot[t] = s;
    __syncthreads();
    for (int d = 1; d < 256; d <<= 1) {
        int v = (t >= d) ? tot[t - d] : 0;
        __syncthreads();
        tot[t] += v;
        __syncthreads();
    }
    int b = (t > 0) ? tot[t - 1] : 0;
#pragma unroll
    for (int j = 0; j < 32; ++j) {
        int i = base + j;
        if (i < n) { off[i] = b + loc[j]; cur[i] = b + loc[j]; }
    }
}

__global__ __launch_bounds__(256) void fill_csr(
    const int* __restrict__ src, const int* __restrict__ dst,
    int* __restrict__ cur, int* __restrict__ eid, int E)
{
    int e = blockIdx.x * 256 + threadIdx.x;
    if (e < E) {
        int p = atomicAdd(&cur[dst[e]], 1);
        eid[p] = src[e];
    }
}

// one block per dst: mean of gathered h rows -> bf16 [hi(D)|lo(D)] at base.
__global__ __launch_bounds__(256) void csr_agg_split(
    const float* __restrict__ h, const int* __restrict__ eid,
    const int* __restrict__ off, const int* __restrict__ cnt,
    ushort* __restrict__ out, int n, int D, int ldout)
{
    int d = blockIdx.x, t = threadIdx.x;
    float a0 = 0.f, a1 = 0.f;
    if (d < n) {
        int base = off[d], k = cnt[d];
        for (int j = 0; j < k; ++j) {
            const float* hr = h + (long)eid[base + j] * D;
            a0 += hr[t];
            if (D == 512) a1 += hr[t + 256];
        }
        float inv = 1.f / fmaxf((float)k, 1.f);
        a0 *= inv; a1 *= inv;
    }
    long ro = (long)d * ldout;
    ushort h0 = bf16_rne(a0);
    out[ro + t] = h0;
    out[ro + D + t] = bf16_rne(a0 - bf16_f32(h0));
    if (D == 512) {
        ushort h1 = bf16_rne(a1);
        out[ro + 256 + t] = h1;
        out[ro + D + 256 + t] = bf16_rne(a1 - bf16_f32(h1));
    }
}

// ------------------------- fused row-wise (D=256) --------------------------
// logsoftmax -> espl split; l2n(logsoftmax) -> splt split. No fp32 writeback.
__global__ __launch_bounds__(256) void logsm_l2n_split(
    const float* __restrict__ h2, ushort* __restrict__ espl,
    ushort* __restrict__ splt)
{
    __shared__ float red[256];
    int i = blockIdx.x, t = threadIdx.x;
    float v = h2[(long)i * 256 + t];
    red[t] = v;
    __syncthreads();
    for (int s = 128; s > 0; s >>= 1) {
        if (t < s) red[t] = fmaxf(red[t], red[t + s]);
        __syncthreads();
    }
    float m = red[0];
    __syncthreads();
    float e = expf(v - m);
    red[t] = e;
    __syncthreads();
    for (int s = 128; s > 0; s >>= 1) {
        if (t < s) red[t] += red[t + s];
        __syncthreads();
    }
    float eb = v - (m + logf(red[0]));
    ushort hh = bf16_rne(eb);
    espl[(long)i * 512 + t] = hh;
    espl[(long)i * 512 + 256 + t] = bf16_rne(eb - bf16_f32(hh));
    __syncthreads();
    red[t] = eb * eb;
    __syncthreads();
    for (int s = 128; s > 0; s >>= 1) {
        if (t < s) red[t] += red[t + s];
        __syncthreads();
    }
    float g = eb / fmaxf(sqrtf(red[0]), 1e-12f);
    ushort gh = bf16_rne(g);
    splt[(long)i * 512 + t] = gh;
    splt[(long)i * 512 + 256 + t] = bf16_rne(g - bf16_f32(gh));
}

__global__ __launch_bounds__(256) void l2n_split(
    const float* __restrict__ in, ushort* __restrict__ splt, int rowoff)
{
    __shared__ float red[256];
    int i = blockIdx.x, t = threadIdx.x;
    float v = in[(long)i * 256 + t];
    red[t] = v * v;
    __syncthreads();
    for (int s = 128; s > 0; s >>= 1) {
        if (t < s) red[t] += red[t + s];
        __syncthreads();
    }
    float g = v / fmaxf(sqrtf(red[0]), 1e-12f);
    ushort gh = bf16_rne(g);
    long ro = (long)(rowoff + i) * 512;
    splt[ro + t] = gh;
    splt[ro + 256 + t] = bf16_rne(g - bf16_f32(gh));
}

__global__ __launch_bounds__(256) void div_rows(
    const float* __restrict__ o1, const float* __restrict__ o2,
    float* __restrict__ loss, int ld, int D, float scale)
{
    __shared__ float r1[256];
    __shared__ float r2[256];
    int i = blockIdx.x, t = threadIdx.x;
    float a = o1[(long)i * ld + t], b = o2[(long)i * ld + t];
    r1[t] = a * a;
    r2[t] = b * b;
    __syncthreads();
    for (int s = 128; s > 0; s >>= 1) {
        if (t < s) { r1[t] += r1[t + s]; r2[t] += r2[t + s]; }
        __syncthreads();
    }
    float na = fmaxf(sqrtf(r1[0]), 1e-12f);
    float nb = fmaxf(sqrtf(r2[0]), 1e-12f);
    __syncthreads();
    float d = a / na - b / nb;
    r1[t] = d * d;
    __syncthreads();
    for (int s = 128; s > 0; s >>= 1) {
        if (t < s) r1[t] += r1[t + s];
        __syncthreads();
    }
    if (t == 0) atomicAdd(loss, r1[0] * scale);
}

// stacked clf: block b: half=b>>11, i=b&2047 (skip i>=2000); row b of p.
__global__ __launch_bounds__(256) void clf2(
    const float* __restrict__ p, const float* __restrict__ Wc1,
    const float* __restrict__ bc1, const float* __restrict__ Wc2,
    const float* __restrict__ bc2, float* __restrict__ out)
{
    __shared__ float v[256];
    __shared__ float hsum[32];
    int b = blockIdx.x, t = threadIdx.x;
    int half = b >> 11, i = b & 2047;
    if (i >= 2000) return;
    v[t] = p[(long)b * 256 + t];
    __syncthreads();
    if (t < 32) {
        float s = bc1[t];
        const float* w = Wc1 + (long)t * 256;
        for (int k = 0; k < 256; ++k) s += v[k] * w[k];
        s = fmaxf(s, 0.f);
        hsum[t] = s * Wc2[t];
    }
    __syncthreads();
    if (t == 0) {
        float s = bc2[0];
        for (int k = 0; k < 32; ++k) s += hsum[k];
        out[(long)i * 2 + half] = s;
    }
}

__global__ void write_loss(const float* __restrict__ loss, float* __restrict__ out)
{
    out[0] = loss[0];
}

// ---------------------------------------------------------------------------
extern "C" void kernel_launch(void* const* d_in, const int* in_sizes, int n_in,
                              void* d_out, int out_size, void* d_ws, size_t ws_size,
                              hipStream_t stream)
{
    constexpr int N1 = 8000, N2 = 2000, IN = 512, HID = 256;

    const float* x   = (const float*)d_in[0];
    const float* ppr = (const float*)d_in[1];
    const int* src0  = (const int*)d_in[2];
    const int* dst0  = (const int*)d_in[3];
    const int* src1  = (const int*)d_in[4];
    const int* dst1  = (const int*)d_in[5];
    const float* Wl0 = (const float*)d_in[8];
    const float* bl0 = (const float*)d_in[9];
    const float* Wr0 = (const float*)d_in[10];
    const float* Wl1 = (const float*)d_in[11];
    const float* bl1 = (const float*)d_in[12];
    const float* Wr1 = (const float*)d_in[13];
    const float* Wa  = (const float*)d_in[14];
    const float* ba  = (const float*)d_in[15];
    const float* Wb  = (const float*)d_in[16];
    const float* bb  = (const float*)d_in[17];
    const float* W1  = (const float*)d_in[18];
    const float* W2  = (const float*)d_in[19];
    const float* Wp1 = (const float*)d_in[20];
    const float* bp1 = (const float*)d_in[21];
    const float* Wp2 = (const float*)d_in[22];
    const float* bp2 = (const float*)d_in[23];
    const float* Wc1 = (const float*)d_in[24];
    const float* bc1 = (const float*)d_in[25];
    const float* Wc2 = (const float*)d_in[26];
    const float* bc2 = (const float*)d_in[27];

    const int E0 = in_sizes[2];
    const int E1 = in_sizes[4];

    float* out = (float*)d_out;              // [2000,2] logits + [1] loss
    float* ws  = (float*)d_ws;
    int*   iws = (int*)d_ws;
    ushort* uws = (ushort*)((char*)d_ws + FEND * sizeof(float));

    auto cdiv = [](int a, int b) { return (a + b - 1) / b; };

    hipMemsetAsync(ws, 0, (size_t)ZEND * sizeof(float), stream);

    // ---- conversions ----
    pack_weights<<<dim3(64, 8), 256, 0, stream>>>(
        Wr0, Wl0, Wr1, Wl1, W1, W2, Wa, Wb, Wp1, Wp2, uws);
    cvt_ppr<<<2048, 256, 0, stream>>>(ppr, uws + U_PPRB, uws + U_PPR2B);
    transpose_cvt<<<dim3(16, 250), 256, 0, stream>>>(x, uws + U_XTB, N1, IN, 8000);
    cvt_x_a0<<<8064, 256, 0, stream>>>(x, uws + U_A0);

    // ---- SAGE layer 0: CSR + fused K GEMM ----
    hist_i<<<cdiv(E0, 256), 256, 0, stream>>>(dst0, iws + ZCNT0, E0);
    scan_excl<<<1, 256, 0, stream>>>(iws + ZCNT0, iws + OFF0, iws + CUR0, N1);
    fill_csr<<<cdiv(E0, 256), 256, 0, stream>>>(src0, dst0, iws + CUR0, iws + EID0, E0);
    csr_agg_split<<<8064, 256, 0, stream>>>(
        x, iws + EID0, iws + OFF0, iws + ZCNT0, uws + U_A0 + 512, N1, IN, 1536);
    // H1 = relu([x|agg_hi|agg_lo] @ [Wr0|Wl0|Wl0]^T + bl0); split rows<2048 -> A1
    mfma128<<<dim3(2, 63), 256, 0, stream>>>(
        uws + U_A0, uws + U_WC0, ws + H1F, uws + U_A1, bl0,
        1536, 1536, 1536, 256, 1024, 256, 2048, 3);

    // ---- SAGE layer 1 ----
    hist_i<<<cdiv(E1, 256), 256, 0, stream>>>(dst1, iws + ZCNT1, E1);
    scan_excl<<<1, 256, 0, stream>>>(iws + ZCNT1, iws + OFF1, iws + CUR1, N2);
    fill_csr<<<cdiv(E1, 256), 256, 0, stream>>>(src1, dst1, iws + CUR1, iws + EID1, E1);
    csr_agg_split<<<2048, 256, 0, stream>>>(
        ws + H1F, iws + EID1, iws + OFF1, iws + ZCNT1, uws + U_A1 + 512, N2, HID, 1024);
    // H2 = [h1_hi|h1_lo|agg_hi|agg_lo] @ [Wr1|Wr1|Wl1|Wl1]^T + bl1
    mfma128<<<dim3(2, 16), 256, 0, stream>>>(
        uws + U_A1, uws + U_WC1, ws + H2F, nullptr, bl1,
        1024, 1024, 1024, 256, 0, 0, 0, 0);
    logsm_l2n_split<<<N2, 256, 0, stream>>>(ws + H2F, uws + U_ESPL, uws + U_SPLT);

    // ---- divergence loss ----
    mfma128<<<dim3(4, 16), 256, 0, stream>>>(
        uws + U_ESPL, uws + U_BD, ws + DIVCF, nullptr, nullptr,
        512, 512, 512, 512, 0, 0, 0, 0);
    div_rows<<<N2, 256, 0, stream>>>(ws + DIVCF, ws + DIVCF + 256, ws + ZLOSS,
                                     512, HID, 1.0f / N2);

    // ---- PPR branch ----
    mfma_bt_sk<<<dim3(4, 16, 5), 256, 0, stream>>>(
        uws + U_PPRB, uws + U_XTB, ws + PART, 8000, 1600, 8000, 8000, 512);
    reduce_split<<<4096, 256, 0, stream>>>(ws + PART, uws + U_XPS, 1048576L, 5);
    // xpa = relu([xp1_hi|xp1_lo] @ [Wa|Wa]^T + ba) -> plain bf16
    mfma128<<<dim3(4, 16), 256, 0, stream>>>(
        uws + U_XPS, uws + U_WAD, nullptr, uws + U_XPAB, ba,
        1024, 1024, 1024, 512, 512, 0, 2048, 1);
    transpose_bf16<<<dim3(16, 64), 256, 0, stream>>>(uws + U_XPAB, uws + U_XPATB, 2048, 512);
    mfma_bt_sk<<<dim3(4, 16, 2), 256, 0, stream>>>(
        uws + U_PPR2B, uws + U_XPATB, ws + PART, 2048, 1024, 2048, 2048, 512);
    reduce_split<<<4096, 256, 0, stream>>>(ws + PART, uws + U_XPS, 1048576L, 2);
    // xpb = [xp2_hi|xp2_lo] @ [Wb|Wb]^T + bb
    mfma128<<<dim3(2, 16), 256, 0, stream>>>(
        uws + U_XPS, uws + U_WBD, ws + XPBF, nullptr, bb,
        1024, 1024, 1024, 256, 0, 0, 0, 0);
    l2n_split<<<N2, 256, 0, stream>>>(ws + XPBF, uws + U_SPLT, 2048);

    // ---- stacked proj + clf over [g1 ; g2] ----
    mfma128<<<dim3(2, 32), 256, 0, stream>>>(
        uws + U_SPLT, uws + U_WP1D, nullptr, uws + U_TSPL, bp1,
        512, 512, 512, 256, 512, 256, 4096, 3);
    mfma128<<<dim3(2, 32), 256, 0, stream>>>(
        uws + U_TSPL, uws + U_WP2D, ws + PB2, nullptr, bp2,
        512, 512, 512, 256, 0, 0, 0, 0);
    clf2<<<4096, 256, 0, stream>>>(ws + PB2, Wc1, bc1, Wc2, bc2, out);

    write_loss<<<1, 1, 0, stream>>>(ws + ZLOSS, out + (long)N2 * 2);
}